// Round 3
// baseline (1220.724 us; speedup 1.0000x reference)
//
#include <hip/hip_runtime.h>
#include <math.h>

#define T_STEPS 64
#define BATCH   512

typedef short s16x8 __attribute__((ext_vector_type(8)));
typedef short s16x4 __attribute__((ext_vector_type(4)));
typedef float f32x4 __attribute__((ext_vector_type(4)));

#define MFMA(a,b,c) __builtin_amdgcn_mfma_f32_16x16x32_bf16((a),(b),(c),0,0,0)

__device__ __forceinline__ short f2bf(float x){
    union { float f; unsigned u; } v; v.f = x;
    unsigned r = v.u + 0x7FFFu + ((v.u >> 16) & 1u);
    return (short)(r >> 16);
}
__device__ __forceinline__ float bf2f(short s){
    union { unsigned u; float f; } v; v.u = ((unsigned)(unsigned short)s) << 16;
    return v.f;
}
__device__ __forceinline__ float frcp(float x){ return __builtin_amdgcn_rcpf(x); }
__device__ __forceinline__ float fsig(float x){ return frcp(1.f + __expf(-x)); }
__device__ __forceinline__ float ftanh(float x){ return 1.f - 2.f*frcp(1.f + __expf(2.f*x)); }
__device__ __forceinline__ float sp(float x){ return (x>20.f)? x : __logf(1.f + __expf(x)); }

// LDS-only barrier: flush this wave's LDS ops, sync. vmcnt NOT drained, no sched pinning.
__device__ __forceinline__ void barx(){
    asm volatile("s_waitcnt lgkmcnt(0)" ::: "memory");
    __builtin_amdgcn_s_barrier();
    asm volatile("" ::: "memory");
}

// ---- packed fragment pool (fragment = 64 lanes x 8 bf16 = 1024B) ----
// frag = base + nt*KT + kt ; elem e of lane l: W[k0 + kt*32+(l>>4)*8+e][nt*16+(l&15)]
#define FR_GRU  0      // w_gru   K=400(13) N=600(38) -> 494
#define FR_INP  494    // w_inp   K=36(2)   N=200(13) -> 26
#define FR_OBSD 520    // w_obsout rows 0:200  K=200(7)  N=200(13) -> 91
#define FR_OBSE 611    // w_obsout rows 200:   K=1024(32) N=200(13) -> 416
#define FR_OBS  1027   // w_obs   K=200(7)  N=60(4)  -> 28
#define FR_IMG  1055   // w_imgout K=200(7) N=200(13) -> 91
#define FR_IMS  1146   // w_ims   K=200(7)  N=60(4)  -> 28
#define FR_TOT  1174

// ws byte offsets
#define WS_STOCH0 1202176
#define WS_DETER0 1202304
#define WS_E      1203200   // E2 bf16 frag layout: [gtile(2048)][nt(13)][lane(64)][r(4)]

__global__ void pack_kernel(const float* w_inp, const float* w_gru, const float* w_imgout,
                            const float* w_obsout, const float* w_ims, const float* w_obs,
                            short* pk){
    int f = blockIdx.x, l = threadIdx.x;
    const float* W; int K, N, ld, KT, k0, rel;
    if      (f < FR_INP ){ W=w_gru;    K=400; N=600; ld=600; KT=13; k0=0;   rel=f; }
    else if (f < FR_OBSD){ W=w_inp;    K=36;  N=200; ld=200; KT=2;  k0=0;   rel=f-FR_INP; }
    else if (f < FR_OBSE){ W=w_obsout; K=200; N=200; ld=200; KT=7;  k0=0;   rel=f-FR_OBSD; }
    else if (f < FR_OBS ){ W=w_obsout; K=1024;N=200; ld=200; KT=32; k0=200; rel=f-FR_OBSE; }
    else if (f < FR_IMG ){ W=w_obs;    K=200; N=60;  ld=60;  KT=7;  k0=0;   rel=f-FR_OBS; }
    else if (f < FR_IMS ){ W=w_imgout; K=200; N=200; ld=200; KT=7;  k0=0;   rel=f-FR_IMG; }
    else                 { W=w_ims;    K=200; N=60;  ld=60;  KT=7;  k0=0;   rel=f-FR_IMS; }
    int nt = rel / KT, kt = rel % KT;
    int col = nt*16 + (l & 15);
    int kb  = kt*32 + (l >> 4)*8;
    s16x8 v;
    #pragma unroll
    for (int e = 0; e < 8; e++){
        int k = kb + e;
        float x = (k < K && col < N) ? W[(size_t)(k + k0)*ld + col] : 0.f;
        v[e] = f2bf(x);
    }
    *(((s16x8*)pk) + (size_t)f*64 + l) = v;
}

__global__ void init_kernel(const float* w_init, const float* w_imgout,
                            const float* ln_img_s, const float* ln_img_b,
                            const float* w_ims, const float* b_ims,
                            float* stoch0, float* deter0){
    __shared__ float d0[200], h0[200], redA[64], redB[64], mv[2];
    int t = threadIdx.x;
    if (t < 200) d0[t] = tanhf(w_init[t]);
    __syncthreads();
    if (t < 200){ float a = 0.f; for (int k = 0; k < 200; k++) a += d0[k]*w_imgout[k*200 + t]; h0[t] = a; }
    __syncthreads();
    if (t < 64){ float s = 0.f, s2 = 0.f;
        for (int j = t; j < 200; j += 64){ float v = h0[j]; s += v; s2 += v*v; }
        redA[t] = s; redB[t] = s2; }
    __syncthreads();
    if (t == 0){ float s = 0.f, s2 = 0.f;
        for (int i = 0; i < 64; i++){ s += redA[i]; s2 += redB[i]; }
        float m = s/200.f, var = s2/200.f - m*m;
        mv[0] = m; mv[1] = rsqrtf(var + 1e-3f); }
    __syncthreads();
    if (t < 200){ float v = (h0[t]-mv[0])*mv[1]*ln_img_s[t] + ln_img_b[t];
        h0[t] = v/(1.f+expf(-v)); }
    __syncthreads();
    if (t < 200) deter0[t] = d0[t];
    if (t < 30){ float a = 0.f; for (int j = 0; j < 200; j++) a += h0[j]*w_ims[j*60 + t];
        stoch0[t] = a + b_ims[t]; }
}

// E2[gtile][nt][lane][r] = fragment-layout embed @ w_obsout[200:,:]
__global__ __launch_bounds__(256) void embed_gemm(const float* embed, const short* pk, short* E2){
    int tid = threadIdx.x; int w = tid >> 6, l = tid & 63;
    int row0 = blockIdx.x*128 + w*32;
    int gt0 = row0 >> 4;
    const float* A0 = embed + (size_t)(row0 + (l & 15))*1024 + (l >> 4)*8;
    const float* A1 = A0 + (size_t)16*1024;
    const s16x8* B = ((const s16x8*)pk) + (size_t)FR_OBSE*64 + l;
    f32x4 acc0[13], acc1[13];
    #pragma unroll
    for (int n = 0; n < 13; n++){ acc0[n] = (f32x4){0.f,0.f,0.f,0.f}; acc1[n] = (f32x4){0.f,0.f,0.f,0.f}; }
    for (int kt = 0; kt < 32; kt++){
        float4 x0 = *(const float4*)(A0 + kt*32), x1 = *(const float4*)(A0 + kt*32 + 4);
        float4 y0 = *(const float4*)(A1 + kt*32), y1 = *(const float4*)(A1 + kt*32 + 4);
        s16x8 af0, af1;
        af0[0]=f2bf(x0.x); af0[1]=f2bf(x0.y); af0[2]=f2bf(x0.z); af0[3]=f2bf(x0.w);
        af0[4]=f2bf(x1.x); af0[5]=f2bf(x1.y); af0[6]=f2bf(x1.z); af0[7]=f2bf(x1.w);
        af1[0]=f2bf(y0.x); af1[1]=f2bf(y0.y); af1[2]=f2bf(y0.z); af1[3]=f2bf(y0.w);
        af1[4]=f2bf(y1.x); af1[5]=f2bf(y1.y); af1[6]=f2bf(y1.z); af1[7]=f2bf(y1.w);
        #pragma unroll
        for (int n = 0; n < 13; n++){
            s16x8 bf = B[(n*32 + kt)*64];
            acc0[n] = MFMA(af0, bf, acc0[n]);
            acc1[n] = MFMA(af1, bf, acc1[n]);
        }
    }
    #pragma unroll
    for (int n = 0; n < 13; n++){
        s16x4 v0, v1;
        #pragma unroll
        for (int r = 0; r < 4; r++){ v0[r] = f2bf(acc0[n][r]); v1[r] = f2bf(acc1[n][r]); }
        *(s16x4*)&E2[(((size_t)gt0*13 + n)*64 + l)*4]       = v0;
        *(s16x4*)&E2[(((size_t)(gt0+1)*13 + n)*64 + l)*4]   = v1;
    }
}

#define ABS_ 424   // bf16: 0:200 x, 200:400 deter, 400:424 zero
#define PBS  612   // f32 parts stride (within U)
#define U1S  210   // f32 xpre/hpre stride (within U)
#define UQS  68    // f32 qpre stride (within U)
#define HOS  232   // bf16 AH stride: A36 cols 0:64 / ho cols 0:200, pad 200:232

__global__ __launch_bounds__(512,1) void scan_kernel(
    const float* __restrict__ action, const float* __restrict__ is_first,
    const float* __restrict__ noise_post,
    const float* __restrict__ ln_inp_s, const float* __restrict__ ln_inp_b,
    const float* __restrict__ ln_obs_s, const float* __restrict__ ln_obs_b,
    const float* __restrict__ b_obs,
    const short* __restrict__ pk, const short* __restrict__ E2,
    const float* __restrict__ stoch0g, const float* __restrict__ deter0g,
    float* __restrict__ out)
{
    __shared__ short Abuf[16*ABS_];   // 13568
    __shared__ float U[16*PBS];       // 39168 (xpre/parts/hpre/qpre union)
    __shared__ short AH[16*HOS];      // 7424  (A36 cols 0:64 / ho union)
    __shared__ float LNP[800];        // 3200: lis,lib,los,lob   => 63360 B

    const int tid = threadIdx.x;
    const int w = tid >> 6, l = tid & 63;
    const int hrow = tid >> 5, s = tid & 31;
    const int r0 = blockIdx.x*16;
    const int rr = (l>>4)*4, cc = l&15;
    const s16x8* PK = (const s16x8*)pk;

    // ---- hoisted scalars ----
    float d0r[7], dreg[7];
    #pragma unroll
    for (int i=0;i<7;i++){ int j=s+32*i; d0r[i] = (j<200)? deter0g[j] : 0.f; dreg[i]=d0r[i]; }
    float st0 = (s<30)? stoch0g[s] : 0.f;
    float bo0 = (s<30)? b_obs[s] : 0.f;
    float bo1 = (s<30)? b_obs[30+s] : 0.f;
    const int aj = (s>=30)? (s-30) : (s<4 ? s+2 : -1);

    // ---- hoisted weights ----
    s16x8 Bi0[2], Bi1[2], Bm3a[7], Bm4[7];
    Bi0[0] = PK[(size_t)(FR_INP + w*2 + 0)*64 + l];
    Bi0[1] = PK[(size_t)(FR_INP + w*2 + 1)*64 + l];
    if (w<5){
        Bi1[0] = PK[(size_t)(FR_INP + (8+w)*2 + 0)*64 + l];
        Bi1[1] = PK[(size_t)(FR_INP + (8+w)*2 + 1)*64 + l];
    }
    #pragma unroll
    for (int kt=0;kt<7;kt++) Bm3a[kt] = PK[(size_t)(FR_OBSD + w*7 + kt)*64 + l];
    if (w>=4){
        #pragma unroll
        for (int kt=0;kt<7;kt++) Bm4[kt] = PK[(size_t)(FR_OBS + (w-4)*7 + kt)*64 + l];
    }

    // ---- running pointers ----
    const float* pIsFn = is_first + 512 + r0;            // points at t+1
    const float* pActn = action + (size_t)(512 + r0)*6;  // points at t+1
    const float* pNz   = noise_post + (size_t)r0*30;     // points at t
    const short* pE2   = E2 + (size_t)(r0>>4)*13*256;    // points at t
    float*       pOut  = out + (size_t)r0*380;           // points at t

    // ---- LDS init / preamble (t=0 state) ----
    for (int idx=tid; idx<800; idx+=512){
        float v;
        if      (idx<200) v = ln_inp_s[idx];
        else if (idx<400) v = ln_inp_b[idx-200];
        else if (idx<600) v = ln_obs_s[idx-400];
        else              v = ln_obs_b[idx-600];
        LNP[idx] = v;
    }
    #pragma unroll
    for (int i=0;i<7;i++){ int j=s+32*i; if (j<200) Abuf[hrow*ABS_+200+j] = f2bf(d0r[i]); }
    for (int idx=tid; idx<16*24; idx+=512) Abuf[(idx/24)*ABS_ + 400 + (idx%24)] = 0;
    for (int idx=tid; idx<16*32; idx+=512) AH[(idx/32)*HOS + 200 + (idx%32)] = 0;
    {
        float f0 = is_first[r0 + hrow];
        float a0 = 0.f;
        if (aj>=0){ float a = action[(size_t)(r0+hrow)*6 + aj]; a0 = a*frcp(fmaxf(fabsf(a),1.f))*(1.f-f0); }
        float stv = (s<30)? st0 : a0;
        AH[hrow*HOS + s] = f2bf(stv);
        AH[hrow*HOS + 32 + s] = f2bf((s<4)? a0 : 0.f);
    }
    barx();

    for (int t=0; t<T_STEPS; t++){
        // ================= P1: prefetch + mm1 =================
        float f_next = pIsFn[hrow];
        float act_n = 0.f;
        if (aj>=0) act_n = pActn[hrow*6 + aj];
        float nz = (s<30)? pNz[hrow*30 + s] : 0.f;
        s16x4 eA = *(const s16x4*)&pE2[(w*64 + l)*4];
        s16x4 eB;
        if (w<5) eB = *(const s16x4*)&pE2[((8+w)*64 + l)*4];

        {
            s16x8 a0 = *(const s16x8*)&AH[cc*HOS + (l>>4)*8];
            s16x8 a1 = *(const s16x8*)&AH[cc*HOS + 32 + (l>>4)*8];
            f32x4 acc = (f32x4){0.f,0.f,0.f,0.f};
            acc = MFMA(a0, Bi0[0], acc);
            acc = MFMA(a1, Bi0[1], acc);
            #pragma unroll
            for (int r=0;r<4;r++) U[(rr+r)*U1S + w*16 + cc] = acc[r];
            if (w<5){
                f32x4 ac2 = (f32x4){0.f,0.f,0.f,0.f};
                ac2 = MFMA(a0, Bi1[0], ac2);
                ac2 = MFMA(a1, Bi1[1], ac2);
                #pragma unroll
                for (int r=0;r<4;r++) U[(rr+r)*U1S + (8+w)*16 + cc] = ac2[r];
            }
        }
        barx(); // B1

        // ================= P2: LN(inp)+silu -> Abuf x =================
        {
            float vals[7], sum=0.f, sq=0.f;
            #pragma unroll
            for (int i=0;i<7;i++){ int j=s+32*i;
                float v = (j<200)? U[hrow*U1S + j] : 0.f;
                vals[i]=v; sum+=v; sq+=v*v; }
            #pragma unroll
            for (int m=16;m>=1;m>>=1){ sum += __shfl_xor(sum,m); sq += __shfl_xor(sq,m); }
            float mean = sum*(1.f/200.f);
            float rstd = rsqrtf(sq*(1.f/200.f) - mean*mean + 1e-3f);
            #pragma unroll
            for (int i=0;i<7;i++){ int j=s+32*i; if (j<200){
                float v = (vals[i]-mean)*rstd*LNP[j] + LNP[200+j];
                Abuf[hrow*ABS_ + j] = f2bf(v*fsig(v));
            }}
        }
        barx(); // B2

        // ================= P3: mm2 [x,deter]@GRU -> parts =================
        {
            s16x8 af[13];
            #pragma unroll
            for (int kt=0;kt<13;kt++) af[kt] = *(const s16x8*)&Abuf[cc*ABS_ + kt*32 + (l>>4)*8];
            #pragma unroll
            for (int it=0; it<5; it++){
                int nt = w + it*8;
                if (nt < 38){
                    const s16x8* Bp = PK + (size_t)(FR_GRU + nt*13)*64 + l;
                    s16x8 b0=Bp[0], b1=Bp[64], b2=Bp[128], b3=Bp[192], b4=Bp[256], b5=Bp[320], b6=Bp[384];
                    s16x8 b7=Bp[448], b8=Bp[512], b9=Bp[576], b10=Bp[640], b11=Bp[704], b12=Bp[768];
                    f32x4 p0={0.f,0.f,0.f,0.f}, p1={0.f,0.f,0.f,0.f};
                    p0 = MFMA(af[0], b0,  p0);  p1 = MFMA(af[1], b1,  p1);
                    p0 = MFMA(af[2], b2,  p0);  p1 = MFMA(af[3], b3,  p1);
                    p0 = MFMA(af[4], b4,  p0);  p1 = MFMA(af[5], b5,  p1);
                    p0 = MFMA(af[6], b6,  p0);  p1 = MFMA(af[7], b7,  p1);
                    p0 = MFMA(af[8], b8,  p0);  p1 = MFMA(af[9], b9,  p1);
                    p0 = MFMA(af[10],b10, p0);  p1 = MFMA(af[11],b11, p1);
                    p0 = MFMA(af[12],b12, p0);
                    #pragma unroll
                    for (int r=0;r<4;r++) U[(rr+r)*PBS + nt*16 + cc] = p0[r]+p1[r];
                }
            }
        }
        barx(); // B3

        // ================= P4: GRU elementwise =================
        {
            float* outp = pOut + hrow*380 + 180;
            #pragma unroll
            for (int i=0;i<7;i++){ int j=s+32*i; if (j<200){
                float rv = U[hrow*PBS + j];
                float cv = U[hrow*PBS + 200 + j];
                float uv = U[hrow*PBS + 400 + j];
                float rg = fsig(rv);
                float cg = ftanh(rg*cv);
                float ug = fsig(uv - 1.f);
                float d  = ug*cg + (1.f-ug)*dreg[i];
                dreg[i] = d;
                Abuf[hrow*ABS_ + 200 + j] = f2bf(d);
                outp[j] = d;
            }}
        }
        barx(); // B4

        // ================= P5: mm3 deter@OBSD, C-init = E =================
        {
            s16x8 Bb[7];
            if (w<5){
                #pragma unroll
                for (int kt=0;kt<7;kt++) Bb[kt] = PK[(size_t)(FR_OBSD + (8+w)*7 + kt)*64 + l];
            }
            s16x8 ad[7];
            #pragma unroll
            for (int kt=0;kt<7;kt++) ad[kt] = *(const s16x8*)&Abuf[cc*ABS_ + 200 + kt*32 + (l>>4)*8];
            {
                f32x4 a0, a1={0.f,0.f,0.f,0.f};
                #pragma unroll
                for (int r=0;r<4;r++) a0[r] = bf2f(eA[r]);
                a0 = MFMA(ad[0], Bm3a[0], a0);
                a1 = MFMA(ad[1], Bm3a[1], a1);
                a0 = MFMA(ad[2], Bm3a[2], a0);
                a1 = MFMA(ad[3], Bm3a[3], a1);
                a0 = MFMA(ad[4], Bm3a[4], a0);
                a1 = MFMA(ad[5], Bm3a[5], a1);
                a0 = MFMA(ad[6], Bm3a[6], a0);
                #pragma unroll
                for (int r=0;r<4;r++) U[(rr+r)*U1S + w*16 + cc] = a0[r]+a1[r];
            }
            if (w<5){
                f32x4 a0, a1={0.f,0.f,0.f,0.f};
                #pragma unroll
                for (int r=0;r<4;r++) a0[r] = bf2f(eB[r]);
                a0 = MFMA(ad[0], Bb[0], a0);
                a1 = MFMA(ad[1], Bb[1], a1);
                a0 = MFMA(ad[2], Bb[2], a0);
                a1 = MFMA(ad[3], Bb[3], a1);
                a0 = MFMA(ad[4], Bb[4], a0);
                a1 = MFMA(ad[5], Bb[5], a1);
                a0 = MFMA(ad[6], Bb[6], a0);
                #pragma unroll
                for (int r=0;r<4;r++) U[(rr+r)*U1S + (8+w)*16 + cc] = a0[r]+a1[r];
            }
        }
        barx(); // B5

        // ================= P6: LN(obs)+silu -> AH (ho) =================
        {
            float vals[7], sum=0.f, sq=0.f;
            #pragma unroll
            for (int i=0;i<7;i++){ int j=s+32*i;
                float v = (j<200)? U[hrow*U1S + j] : 0.f;
                vals[i]=v; sum+=v; sq+=v*v; }
            #pragma unroll
            for (int m=16;m>=1;m>>=1){ sum += __shfl_xor(sum,m); sq += __shfl_xor(sq,m); }
            float mean = sum*(1.f/200.f);
            float rstd = rsqrtf(sq*(1.f/200.f) - mean*mean + 1e-3f);
            #pragma unroll
            for (int i=0;i<7;i++){ int j=s+32*i; if (j<200){
                float v = (vals[i]-mean)*rstd*LNP[400+j] + LNP[600+j];
                AH[hrow*HOS + j] = f2bf(v*fsig(v));
            }}
        }
        barx(); // B6

        // ================= P7: mm4 ho@OBS (waves 4..7) =================
        if (w>=4){
            s16x8 ah[7];
            #pragma unroll
            for (int kt=0;kt<7;kt++) ah[kt] = *(const s16x8*)&AH[cc*HOS + kt*32 + (l>>4)*8];
            f32x4 a0={0.f,0.f,0.f,0.f}, a1={0.f,0.f,0.f,0.f};
            a0 = MFMA(ah[0], Bm4[0], a0);
            a1 = MFMA(ah[1], Bm4[1], a1);
            a0 = MFMA(ah[2], Bm4[2], a0);
            a1 = MFMA(ah[3], Bm4[3], a1);
            a0 = MFMA(ah[4], Bm4[4], a0);
            a1 = MFMA(ah[5], Bm4[5], a1);
            a0 = MFMA(ah[6], Bm4[6], a0);
            int nt = w-4;
            #pragma unroll
            for (int r=0;r<4;r++) U[(rr+r)*UQS + nt*16 + cc] = a0[r]+a1[r];
        }
        barx(); // B7

        // ================= P8: posterior + next-step A36/deter remask =================
        {
            float an = act_n*frcp(fmaxf(fabsf(act_n),1.f))*(1.f - f_next);
            float post = 0.f;
            if (s<30){
                float qm = U[hrow*UQS + s] + bo0;
                float x  = U[hrow*UQS + 30 + s] + bo1;
                float qs = sp(x) + 0.1f;
                post = qm + qs*nz;
                float* op = pOut + hrow*380;
                op[s] = qm; op[30+s] = qs; op[60+s] = post;
            }
            float stv = (s<30)? ((f_next!=0.f)? st0 : post) : an;
            AH[hrow*HOS + s] = f2bf(stv);
            AH[hrow*HOS + 32 + s] = f2bf((s<4)? an : 0.f);
            if (f_next != 0.f){
                #pragma unroll
                for (int i=0;i<7;i++){ int j=s+32*i; if (j<200){
                    dreg[i] = d0r[i];
                    Abuf[hrow*ABS_ + 200 + j] = f2bf(d0r[i]);
                }}
            }
        }
        barx(); // B8

        // pointer bumps
        pNz  += 512*30;
        pE2  += 32*13*256;
        pOut += 512*380;
        if (t < T_STEPS-2){ pIsFn += 512; pActn += 512*6; }
    }
}

// prior head for all (t,b)
__global__ __launch_bounds__(64) void prior_kernel(const float* noise_prior, const float* b_ims,
                                                   const float* ln_img_s, const float* ln_img_b,
                                                   const short* pk, float* out){
    __shared__ short Ab[16*232];
    __shared__ float U[16*212];
    __shared__ short hob[16*224];
    __shared__ float qp[16*68];
    int l = threadIdx.x;
    int g0 = blockIdx.x*16;

    for (int idx = l; idx < 16*232; idx += 64){
        int rr = idx/232, c = idx%232;
        short v = 0;
        if (c < 200) v = f2bf(out[(size_t)(g0 + rr)*380 + 180 + c]);
        Ab[idx] = v;
    }
    __syncthreads();
    {
        s16x8 af[7];
        #pragma unroll
        for (int kt = 0; kt < 7; kt++)
            af[kt] = *(s16x8*)&Ab[(l & 15)*232 + kt*32 + (l >> 4)*8];
        for (int nt = 0; nt < 13; nt++){
            f32x4 acc = (f32x4){0.f,0.f,0.f,0.f};
            const s16x8* B = ((const s16x8*)pk) + (size_t)(FR_IMG + nt*7)*64 + l;
            #pragma unroll
            for (int kt = 0; kt < 7; kt++) acc = MFMA(af[kt], B[kt*64], acc);
            int rr = (l >> 4)*4, cc = l & 15;
            #pragma unroll
            for (int r = 0; r < 4; r++) U[(rr + r)*212 + nt*16 + cc] = acc[r];
        }
    }
    __syncthreads();
    {
        int rw = l >> 2, s4 = l & 3;
        float sum = 0.f, sq = 0.f, vals[50];
        #pragma unroll
        for (int i = 0; i < 50; i++){ int j = s4 + 4*i; float v = U[rw*212 + j];
            vals[i] = v; sum += v; sq += v*v; }
        sum += __shfl_xor(sum, 1); sq += __shfl_xor(sq, 1);
        sum += __shfl_xor(sum, 2); sq += __shfl_xor(sq, 2);
        float mean = sum/200.f, var = sq/200.f - mean*mean, rstd = rsqrtf(var + 1e-3f);
        #pragma unroll
        for (int i = 0; i < 50; i++){ int j = s4 + 4*i;
            float v = (vals[i] - mean)*rstd*ln_img_s[j] + ln_img_b[j];
            hob[rw*224 + j] = f2bf(v*fsig(v));
        }
    }
    for (int idx = l; idx < 16*24; idx += 64){ int rr = idx/24; hob[rr*224 + 200 + idx%24] = 0; }
    __syncthreads();
    for (int nt = 0; nt < 4; nt++){
        s16x8 af[7];
        #pragma unroll
        for (int kt = 0; kt < 7; kt++)
            af[kt] = *(s16x8*)&hob[(l & 15)*224 + kt*32 + (l >> 4)*8];
        f32x4 acc = (f32x4){0.f,0.f,0.f,0.f};
        const s16x8* B = ((const s16x8*)pk) + (size_t)(FR_IMS + nt*7)*64 + l;
        #pragma unroll
        for (int kt = 0; kt < 7; kt++) acc = MFMA(af[kt], B[kt*64], acc);
        int rr = (l >> 4)*4, cc = l & 15;
        #pragma unroll
        for (int r = 0; r < 4; r++) qp[(rr + r)*68 + nt*16 + cc] = acc[r];
    }
    __syncthreads();
    for (int idx = l; idx < 480; idx += 64){
        int rw = idx/30, j = idx%30;
        float pm = qp[rw*68 + j] + b_ims[j];
        float x  = qp[rw*68 + 30 + j] + b_ims[30 + j];
        float ps = sp(x) + 0.1f;
        float nz = noise_prior[(size_t)(g0 + rw)*30 + j];
        float prior = pm + ps*nz;
        float* op = out + (size_t)(g0 + rw)*380;
        op[90 + j] = pm; op[120 + j] = ps; op[150 + j] = prior;
    }
}

extern "C" void kernel_launch(void* const* d_in, const int* in_sizes, int n_in,
                              void* d_out, int out_size, void* d_ws, size_t ws_size,
                              hipStream_t stream){
    const float* embed    = (const float*)d_in[0];
    const float* action   = (const float*)d_in[1];
    const float* is_first = (const float*)d_in[2];
    const float* nzp      = (const float*)d_in[3];
    const float* nzq      = (const float*)d_in[4];
    const float* w_inp    = (const float*)d_in[5];
    const float* ln_inp_s = (const float*)d_in[6];
    const float* ln_inp_b = (const float*)d_in[7];
    const float* w_gru    = (const float*)d_in[8];
    const float* w_imgout = (const float*)d_in[9];
    const float* ln_img_s = (const float*)d_in[10];
    const float* ln_img_b = (const float*)d_in[11];
    const float* w_obsout = (const float*)d_in[12];
    const float* ln_obs_s = (const float*)d_in[13];
    const float* ln_obs_b = (const float*)d_in[14];
    const float* w_ims    = (const float*)d_in[15];
    const float* b_ims    = (const float*)d_in[16];
    const float* w_obs    = (const float*)d_in[17];
    const float* b_obs    = (const float*)d_in[18];
    const float* w_init   = (const float*)d_in[19];

    char*  ws     = (char*)d_ws;
    short* pk     = (short*)ws;
    float* stoch0 = (float*)(ws + WS_STOCH0);
    float* deter0 = (float*)(ws + WS_DETER0);
    short* E2     = (short*)(ws + WS_E);
    float* out    = (float*)d_out;

    hipLaunchKernelGGL(pack_kernel, dim3(FR_TOT), dim3(64), 0, stream,
                       w_inp, w_gru, w_imgout, w_obsout, w_ims, w_obs, pk);
    hipLaunchKernelGGL(init_kernel, dim3(1), dim3(256), 0, stream,
                       w_init, w_imgout, ln_img_s, ln_img_b, w_ims, b_ims, stoch0, deter0);
    hipLaunchKernelGGL(embed_gemm, dim3(256), dim3(256), 0, stream, embed, pk, E2);
    hipLaunchKernelGGL(scan_kernel, dim3(32), dim3(512), 0, stream,
                       action, is_first, nzq, ln_inp_s, ln_inp_b, ln_obs_s, ln_obs_b, b_obs,
                       pk, E2, stoch0, deter0, out);
    hipLaunchKernelGGL(prior_kernel, dim3(2048), dim3(64), 0, stream, nzp, b_ims, ln_img_s, ln_img_b, pk, out);
}

// Round 4
// 1186.339 us; speedup vs baseline: 1.0290x; 1.0290x over previous
//
#include <hip/hip_runtime.h>
#include <math.h>

#define T_STEPS 64
#define BATCH   512

typedef short s16x8 __attribute__((ext_vector_type(8)));
typedef float f32x4 __attribute__((ext_vector_type(4)));

#define MFMA(a,b,c) __builtin_amdgcn_mfma_f32_16x16x32_bf16((a),(b),(c),0,0,0)

__device__ __forceinline__ short f2bf(float x){
    union { float f; unsigned u; } v; v.f = x;
    unsigned r = v.u + 0x7FFFu + ((v.u >> 16) & 1u);
    return (short)(r >> 16);
}
__device__ __forceinline__ float bf2f(short s){
    union { unsigned u; float f; } v; v.u = ((unsigned)(unsigned short)s) << 16;
    return v.f;
}
__device__ __forceinline__ float sigm(float x){ return 1.f/(1.f+__expf(-x)); }
__device__ __forceinline__ float sp(float x){ return (x>20.f)? x : log1pf(expf(x)); }

// ---- packed fragment bases (fragment = 64 lanes x 8 bf16 = 1024B) ----
// layout: frag index = base + nt*KT + kt ; within frag: lane*8 shorts
// B-frag element e of lane l: W[k = kt*32 + (l>>4)*8 + e][col = nt*16 + (l&15)]
#define FR_GRU   0      // w_gru   K=400(13) N=600(38)  -> 494
#define FR_INP   494    // w_inp   K=36 (2)  N=200(13)  -> 26
#define FR_OBSD  520    // w_obsout[0:200]   K=200(7) N=200(13) -> 91
#define FR_OBSE  611    // w_obsout[200:]    K=1024(32) N=200(13) -> 416
#define FR_OBS   1027   // w_obs   K=200(7)  N=60(4)   -> 28
#define FR_IMG   1055   // w_imgout K=200(7) N=200(13) -> 91
#define FR_IMS   1146   // w_ims   K=200(7)  N=60(4)   -> 28
#define FR_TOT   1174

// ws byte offsets
#define WS_STOCH0 1202176
#define WS_DETER0 1202304
#define WS_E      1203200   // bf16 E[32768][200] = 13,107,200 B

__global__ void pack_kernel(const float* w_inp, const float* w_gru, const float* w_imgout,
                            const float* w_obsout, const float* w_ims, const float* w_obs,
                            short* pk){
    int f = blockIdx.x, l = threadIdx.x;
    const float* W; int K, N, ld, KT, k0, rel;
    if      (f < FR_INP ){ W=w_gru;    K=400; N=600; ld=600; KT=13; k0=0;   rel=f; }
    else if (f < FR_OBSD){ W=w_inp;    K=36;  N=200; ld=200; KT=2;  k0=0;   rel=f-FR_INP; }
    else if (f < FR_OBSE){ W=w_obsout; K=200; N=200; ld=200; KT=7;  k0=0;   rel=f-FR_OBSD; }
    else if (f < FR_OBS ){ W=w_obsout; K=1024;N=200; ld=200; KT=32; k0=200; rel=f-FR_OBSE; }
    else if (f < FR_IMG ){ W=w_obs;    K=200; N=60;  ld=60;  KT=7;  k0=0;   rel=f-FR_OBS; }
    else if (f < FR_IMS ){ W=w_imgout; K=200; N=200; ld=200; KT=7;  k0=0;   rel=f-FR_IMG; }
    else                 { W=w_ims;    K=200; N=60;  ld=60;  KT=7;  k0=0;   rel=f-FR_IMS; }
    int nt = rel / KT, kt = rel % KT;
    int col = nt*16 + (l & 15);
    int kb  = kt*32 + (l >> 4)*8;
    s16x8 v;
    #pragma unroll
    for (int e = 0; e < 8; e++){
        int k = kb + e;
        float x = (k < K && col < N) ? W[(size_t)(k + k0)*ld + col] : 0.f;
        v[e] = f2bf(x);
    }
    *(((s16x8*)pk) + (size_t)f*64 + l) = v;
}

__global__ void init_kernel(const float* w_init, const float* w_imgout,
                            const float* ln_img_s, const float* ln_img_b,
                            const float* w_ims, const float* b_ims,
                            float* stoch0, float* deter0){
    __shared__ float d0[200], h0[200], redA[64], redB[64], mv[2];
    int t = threadIdx.x;
    if (t < 200) d0[t] = tanhf(w_init[t]);
    __syncthreads();
    if (t < 200){ float a = 0.f; for (int k = 0; k < 200; k++) a += d0[k]*w_imgout[k*200 + t]; h0[t] = a; }
    __syncthreads();
    if (t < 64){ float s = 0.f, s2 = 0.f;
        for (int j = t; j < 200; j += 64){ float v = h0[j]; s += v; s2 += v*v; }
        redA[t] = s; redB[t] = s2; }
    __syncthreads();
    if (t == 0){ float s = 0.f, s2 = 0.f;
        for (int i = 0; i < 64; i++){ s += redA[i]; s2 += redB[i]; }
        float m = s/200.f, var = s2/200.f - m*m;
        mv[0] = m; mv[1] = rsqrtf(var + 1e-3f); }
    __syncthreads();
    if (t < 200){ float v = (h0[t]-mv[0])*mv[1]*ln_img_s[t] + ln_img_b[t];
        h0[t] = v/(1.f+expf(-v)); }
    __syncthreads();
    if (t < 200) deter0[t] = d0[t];
    if (t < 30){ float a = 0.f; for (int j = 0; j < 200; j++) a += h0[j]*w_ims[j*60 + t];
        stoch0[t] = a + b_ims[t]; }
}

// E[t,b,:] = embed[t,b,:] @ w_obsout[200:1224,:]   (bf16 result)
__global__ __launch_bounds__(256) void embed_gemm(const float* embed, const short* pk, short* E){
    int tid = threadIdx.x; int w = tid >> 6, l = tid & 63;
    int row0 = blockIdx.x*128 + w*32;
    const float* A0 = embed + (size_t)(row0 + (l & 15))*1024 + (l >> 4)*8;
    const float* A1 = A0 + (size_t)16*1024;
    const s16x8* B = ((const s16x8*)pk) + (size_t)FR_OBSE*64 + l;
    f32x4 acc0[13], acc1[13];
    #pragma unroll
    for (int n = 0; n < 13; n++){ acc0[n] = (f32x4){0.f,0.f,0.f,0.f}; acc1[n] = (f32x4){0.f,0.f,0.f,0.f}; }
    for (int kt = 0; kt < 32; kt++){
        float4 x0 = *(const float4*)(A0 + kt*32), x1 = *(const float4*)(A0 + kt*32 + 4);
        float4 y0 = *(const float4*)(A1 + kt*32), y1 = *(const float4*)(A1 + kt*32 + 4);
        s16x8 af0, af1;
        af0[0]=f2bf(x0.x); af0[1]=f2bf(x0.y); af0[2]=f2bf(x0.z); af0[3]=f2bf(x0.w);
        af0[4]=f2bf(x1.x); af0[5]=f2bf(x1.y); af0[6]=f2bf(x1.z); af0[7]=f2bf(x1.w);
        af1[0]=f2bf(y0.x); af1[1]=f2bf(y0.y); af1[2]=f2bf(y0.z); af1[3]=f2bf(y0.w);
        af1[4]=f2bf(y1.x); af1[5]=f2bf(y1.y); af1[6]=f2bf(y1.z); af1[7]=f2bf(y1.w);
        #pragma unroll
        for (int n = 0; n < 13; n++){
            s16x8 bf = B[(n*32 + kt)*64];
            acc0[n] = MFMA(af0, bf, acc0[n]);
            acc1[n] = MFMA(af1, bf, acc1[n]);
        }
    }
    int rr = (l >> 4)*4, cc = l & 15;
    #pragma unroll
    for (int n = 0; n < 13; n++){
        int col = n*16 + cc;
        if (col < 200){
            #pragma unroll
            for (int r = 0; r < 4; r++){
                E[(size_t)(row0 + rr + r)*200 + col]        = f2bf(acc0[n][r]);
                E[(size_t)(row0 + 16 + rr + r)*200 + col]   = f2bf(acc1[n][r]);
            }
        }
    }
}

#define AB_STRIDE 424   // bf16; cols 0:200 x, 200:400 deter, 400:424 zero
#define XP_STRIDE 212   // f32 within union U
#define PT_STRIDE 612   // f32 within union U
#define QP_STRIDE 68
#define A36_STRIDE 72   // bf16 within A36/hobuf union
#define HO_STRIDE 224

__global__ __launch_bounds__(1024) void scan_kernel(
    const float* action, const float* is_first, const float* noise_post,
    const float* ln_inp_s, const float* ln_inp_b,
    const float* ln_obs_s, const float* ln_obs_b,
    const float* b_obs,
    const short* pk, const short* E, const float* stoch0g, const float* deter0g,
    float* out)
{
    __shared__ short Abuf[16*AB_STRIDE];     // 13568 B
    __shared__ float U[16*PT_STRIDE];        // 39168 B (xpre/parts/hpre/qpre union)
    __shared__ short A36hob[16*HO_STRIDE];   // 7168 B (A36 / hobuf union)
    __shared__ float Sbuf[16*30];            // 1920 B

    int tid = threadIdx.x;
    int w = tid >> 6, l = tid & 63;
    int row = tid >> 5, s = tid & 31;
    int r0 = blockIdx.x*16;

    float dreg[7];
    #pragma unroll
    for (int i = 0; i < 7; i++){ int j = s + 32*i; dreg[i] = (j < 200) ? deter0g[j] : 0.f; }
    if (tid < 512){
        if (s < 30) Sbuf[row*30 + s] = stoch0g[s];
    }
    for (int idx = tid; idx < 16*24; idx += 1024){ int rr = idx/24; Abuf[rr*AB_STRIDE + 400 + idx%24] = 0; }
    if (tid < 512){
        #pragma unroll
        for (int i = 0; i < 7; i++){ int j = s + 32*i; if (j < 200) Abuf[row*AB_STRIDE + 200 + j] = f2bf(dreg[i]); }
    }
    __syncthreads();

    for (int t = 0; t < T_STEPS; t++){
        // ---- stage 1: is_first masking, build A36, prefetch E ----
        if (tid < 512){
            float f = is_first[(size_t)t*BATCH + r0 + row];
            #pragma unroll
            for (int i = 0; i < 7; i++){ int j = s + 32*i; if (j < 200){
                float d = dreg[i]*(1.f - f) + deter0g[j]*f;
                dreg[i] = d;
                Abuf[row*AB_STRIDE + 200 + j] = f2bf(d);
            }}
            for (int j = s; j < 64; j += 32){
                float v = 0.f;
                if (j < 30) v = Sbuf[row*30 + j]*(1.f - f) + stoch0g[j]*f;
                else if (j < 36){
                    float a = action[(size_t)((size_t)t*BATCH + r0 + row)*6 + (j - 30)];
                    a = a / fmaxf(fabsf(a), 1.f);
                    v = a*(1.f - f);
                }
                A36hob[row*A36_STRIDE + j] = f2bf(v);
            }
        }
        s16x8 Ech;
        if (tid < 400){
            int er = tid/25, eq = tid%25;
            Ech = *(((const s16x8*)(E + (size_t)((size_t)t*BATCH + r0 + er)*200)) + eq);
        }
        __syncthreads(); // B1

        // ---- mm1: A36 @ w_inp -> xpre (waves 0..12, one nt each) ----
        if (w < 13){
            s16x8 a0 = *(s16x8*)&A36hob[(l & 15)*A36_STRIDE + (l >> 4)*8];
            s16x8 a1 = *(s16x8*)&A36hob[(l & 15)*A36_STRIDE + 32 + (l >> 4)*8];
            int nt = w;
            f32x4 acc = (f32x4){0.f,0.f,0.f,0.f};
            const s16x8* B = ((const s16x8*)pk) + (size_t)(FR_INP + nt*2)*64 + l;
            acc = MFMA(a0, B[0],  acc);
            acc = MFMA(a1, B[64], acc);
            int rr = (l >> 4)*4, cc = l & 15;
            #pragma unroll
            for (int r = 0; r < 4; r++) U[(rr + r)*XP_STRIDE + nt*16 + cc] = acc[r];
        }
        __syncthreads(); // B2

        // ---- stage 3: LN(inp)+silu -> Abuf[:,0:200] bf16 ----
        if (tid < 512){
            float sum = 0.f, sq = 0.f, vals[7];
            #pragma unroll
            for (int i = 0; i < 7; i++){ int j = s + 32*i;
                float v = (j < 200) ? U[row*XP_STRIDE + j] : 0.f;
                vals[i] = v; sum += v; sq += v*v; }
            #pragma unroll
            for (int m = 16; m >= 1; m >>= 1){ sum += __shfl_xor(sum, m); sq += __shfl_xor(sq, m); }
            float mean = sum/200.f, var = sq/200.f - mean*mean, rstd = rsqrtf(var + 1e-3f);
            #pragma unroll
            for (int i = 0; i < 7; i++){ int j = s + 32*i; if (j < 200){
                float v = (vals[i] - mean)*rstd*ln_inp_s[j] + ln_inp_b[j];
                float y = v/(1.f + expf(-v));
                Abuf[row*AB_STRIDE + j] = f2bf(y);
            }}
        }
        __syncthreads(); // B3

        // ---- mm2: [x,deter] @ w_gru -> parts (16 waves, 2-3 nt each) ----
        {
            s16x8 af[13];
            #pragma unroll
            for (int kt = 0; kt < 13; kt++)
                af[kt] = *(s16x8*)&Abuf[(l & 15)*AB_STRIDE + kt*32 + (l >> 4)*8];
            int ntlo = (w*38) >> 4, nthi = ((w+1)*38) >> 4;
            for (int nt = ntlo; nt < nthi; nt++){
                f32x4 acc = (f32x4){0.f,0.f,0.f,0.f};
                const s16x8* B = ((const s16x8*)pk) + (size_t)(FR_GRU + nt*13)*64 + l;
                #pragma unroll
                for (int kt = 0; kt < 13; kt++) acc = MFMA(af[kt], B[kt*64], acc);
                int rr = (l >> 4)*4, cc = l & 15;
                #pragma unroll
                for (int r = 0; r < 4; r++) U[(rr + r)*PT_STRIDE + nt*16 + cc] = acc[r];
            }
        }
        __syncthreads(); // B4

        // ---- stage 5: GRU elementwise, update deter ----
        if (tid < 512){
            float* outp = out + (size_t)((size_t)t*BATCH + r0 + row)*380;
            #pragma unroll
            for (int i = 0; i < 7; i++){ int j = s + 32*i; if (j < 200){
                float rv = U[row*PT_STRIDE + j];
                float cv = U[row*PT_STRIDE + 200 + j];
                float uv = U[row*PT_STRIDE + 400 + j];
                float rg = 1.f/(1.f + expf(-rv));
                float cg = tanhf(rg*cv);
                float ug = 1.f/(1.f + expf(-(uv - 1.f)));
                float d  = ug*cg + (1.f - ug)*dreg[i];
                dreg[i] = d;
                Abuf[row*AB_STRIDE + 200 + j] = f2bf(d);
                outp[180 + j] = d;
            }}
        }
        __syncthreads(); // B5

        // ---- mm3: deter @ w_obsout[0:200] -> hpre (waves 0..12, one nt each) ----
        if (w < 13){
            s16x8 af[7];
            #pragma unroll
            for (int kt = 0; kt < 7; kt++)
                af[kt] = *(s16x8*)&Abuf[(l & 15)*AB_STRIDE + 200 + kt*32 + (l >> 4)*8];
            int nt = w;
            f32x4 acc = (f32x4){0.f,0.f,0.f,0.f};
            const s16x8* B = ((const s16x8*)pk) + (size_t)(FR_OBSD + nt*7)*64 + l;
            #pragma unroll
            for (int kt = 0; kt < 7; kt++) acc = MFMA(af[kt], B[kt*64], acc);
            int rr = (l >> 4)*4, cc = l & 15;
            #pragma unroll
            for (int r = 0; r < 4; r++) U[(rr + r)*XP_STRIDE + nt*16 + cc] = acc[r];
        }
        __syncthreads(); // B6

        // ---- stage 7: += E ----
        if (tid < 400){
            int er = tid/25, eq = tid%25;
            #pragma unroll
            for (int e = 0; e < 8; e++) U[er*XP_STRIDE + eq*8 + e] += bf2f(Ech[e]);
        }
        __syncthreads(); // B7

        // ---- stage 8: LN(obs)+silu -> hobuf bf16 ----
        if (tid < 512){
            float sum = 0.f, sq = 0.f, vals[7];
            #pragma unroll
            for (int i = 0; i < 7; i++){ int j = s + 32*i;
                float v = (j < 200) ? U[row*XP_STRIDE + j] : 0.f;
                vals[i] = v; sum += v; sq += v*v; }
            #pragma unroll
            for (int m = 16; m >= 1; m >>= 1){ sum += __shfl_xor(sum, m); sq += __shfl_xor(sq, m); }
            float mean = sum/200.f, var = sq/200.f - mean*mean, rstd = rsqrtf(var + 1e-3f);
            #pragma unroll
            for (int i = 0; i < 7; i++){ int j = s + 32*i;
                short hv = 0;
                if (j < 200){
                    float v = (vals[i] - mean)*rstd*ln_obs_s[j] + ln_obs_b[j];
                    float y = v/(1.f + expf(-v));
                    hv = f2bf(y);
                }
                A36hob[row*HO_STRIDE + j] = hv;
            }
        }
        __syncthreads(); // B8

        // ---- mm4: ho @ w_obs -> qpre (waves 12..15, one nt each) ----
        if (w >= 12){
            s16x8 af[7];
            #pragma unroll
            for (int kt = 0; kt < 7; kt++)
                af[kt] = *(s16x8*)&A36hob[(l & 15)*HO_STRIDE + kt*32 + (l >> 4)*8];
            int nt = w - 12;
            f32x4 acc = (f32x4){0.f,0.f,0.f,0.f};
            const s16x8* B = ((const s16x8*)pk) + (size_t)(FR_OBS + nt*7)*64 + l;
            #pragma unroll
            for (int kt = 0; kt < 7; kt++) acc = MFMA(af[kt], B[kt*64], acc);
            int rr = (l >> 4)*4, cc = l & 15;
            #pragma unroll
            for (int r = 0; r < 4; r++) U[(rr + r)*QP_STRIDE + nt*16 + cc] = acc[r];
        }
        __syncthreads(); // B9

        // ---- stage 10: posterior stats + carry ----
        if (tid < 480){
            int rw = tid/30, j = tid%30;
            float qm = U[rw*QP_STRIDE + j] + b_obs[j];
            float x  = U[rw*QP_STRIDE + 30 + j] + b_obs[30 + j];
            float qs = sp(x) + 0.1f;
            float nz = noise_post[(size_t)((size_t)t*BATCH + r0 + rw)*30 + j];
            float post = qm + qs*nz;
            float* outp = out + (size_t)((size_t)t*BATCH + r0 + rw)*380;
            outp[j] = qm; outp[30 + j] = qs; outp[60 + j] = post;
            Sbuf[rw*30 + j] = post;
        }
        __syncthreads(); // B10
    }
}

// prior head for all (t,b): hp = silu(LN(deter@w_imgout)); pm,ps,prior
__global__ __launch_bounds__(64) void prior_kernel(const float* noise_prior, const float* b_ims,
                                                   const float* ln_img_s, const float* ln_img_b,
                                                   const short* pk, float* out){
    __shared__ short Ab[16*232];
    __shared__ float U[16*212];
    __shared__ short hob[16*224];
    __shared__ float qp[16*68];
    int l = threadIdx.x;
    int g0 = blockIdx.x*16;

    for (int idx = l; idx < 16*232; idx += 64){
        int rr = idx/232, c = idx%232;
        short v = 0;
        if (c < 200) v = f2bf(out[(size_t)(g0 + rr)*380 + 180 + c]);
        Ab[idx] = v;
    }
    __syncthreads();
    {
        s16x8 af[7];
        #pragma unroll
        for (int kt = 0; kt < 7; kt++)
            af[kt] = *(s16x8*)&Ab[(l & 15)*232 + kt*32 + (l >> 4)*8];
        for (int nt = 0; nt < 13; nt++){
            f32x4 acc = (f32x4){0.f,0.f,0.f,0.f};
            const s16x8* B = ((const s16x8*)pk) + (size_t)(FR_IMG + nt*7)*64 + l;
            #pragma unroll
            for (int kt = 0; kt < 7; kt++) acc = MFMA(af[kt], B[kt*64], acc);
            int rr = (l >> 4)*4, cc = l & 15;
            #pragma unroll
            for (int r = 0; r < 4; r++) U[(rr + r)*212 + nt*16 + cc] = acc[r];
        }
    }
    __syncthreads();
    {
        int rw = l >> 2, s4 = l & 3;
        float sum = 0.f, sq = 0.f, vals[50];
        #pragma unroll
        for (int i = 0; i < 50; i++){ int j = s4 + 4*i; float v = U[rw*212 + j];
            vals[i] = v; sum += v; sq += v*v; }
        sum += __shfl_xor(sum, 1); sq += __shfl_xor(sq, 1);
        sum += __shfl_xor(sum, 2); sq += __shfl_xor(sq, 2);
        float mean = sum/200.f, var = sq/200.f - mean*mean, rstd = rsqrtf(var + 1e-3f);
        #pragma unroll
        for (int i = 0; i < 50; i++){ int j = s4 + 4*i;
            float v = (vals[i] - mean)*rstd*ln_img_s[j] + ln_img_b[j];
            hob[rw*224 + j] = f2bf(v/(1.f + expf(-v)));
        }
    }
    for (int idx = l; idx < 16*24; idx += 64){ int rr = idx/24; hob[rr*224 + 200 + idx%24] = 0; }
    __syncthreads();
    for (int nt = 0; nt < 4; nt++){
        s16x8 af[7];
        #pragma unroll
        for (int kt = 0; kt < 7; kt++)
            af[kt] = *(s16x8*)&hob[(l & 15)*224 + kt*32 + (l >> 4)*8];
        f32x4 acc = (f32x4){0.f,0.f,0.f,0.f};
        const s16x8* B = ((const s16x8*)pk) + (size_t)(FR_IMS + nt*7)*64 + l;
        #pragma unroll
        for (int kt = 0; kt < 7; kt++) acc = MFMA(af[kt], B[kt*64], acc);
        int rr = (l >> 4)*4, cc = l & 15;
        #pragma unroll
        for (int r = 0; r < 4; r++) qp[(rr + r)*68 + nt*16 + cc] = acc[r];
    }
    __syncthreads();
    for (int idx = l; idx < 480; idx += 64){
        int rw = idx/30, j = idx%30;
        float pm = qp[rw*68 + j] + b_ims[j];
        float x  = qp[rw*68 + 30 + j] + b_ims[30 + j];
        float ps = sp(x) + 0.1f;
        float nz = noise_prior[(size_t)(g0 + rw)*30 + j];
        float prior = pm + ps*nz;
        float* op = out + (size_t)(g0 + rw)*380;
        op[90 + j] = pm; op[120 + j] = ps; op[150 + j] = prior;
    }
}

extern "C" void kernel_launch(void* const* d_in, const int* in_sizes, int n_in,
                              void* d_out, int out_size, void* d_ws, size_t ws_size,
                              hipStream_t stream){
    const float* embed    = (const float*)d_in[0];
    const float* action   = (const float*)d_in[1];
    const float* is_first = (const float*)d_in[2];
    const float* nzp      = (const float*)d_in[3];
    const float* nzq      = (const float*)d_in[4];
    const float* w_inp    = (const float*)d_in[5];
    const float* ln_inp_s = (const float*)d_in[6];
    const float* ln_inp_b = (const float*)d_in[7];
    const float* w_gru    = (const float*)d_in[8];
    const float* w_imgout = (const float*)d_in[9];
    const float* ln_img_s = (const float*)d_in[10];
    const float* ln_img_b = (const float*)d_in[11];
    const float* w_obsout = (const float*)d_in[12];
    const float* ln_obs_s = (const float*)d_in[13];
    const float* ln_obs_b = (const float*)d_in[14];
    const float* w_ims    = (const float*)d_in[15];
    const float* b_ims    = (const float*)d_in[16];
    const float* w_obs    = (const float*)d_in[17];
    const float* b_obs    = (const float*)d_in[18];
    const float* w_init   = (const float*)d_in[19];

    char*  ws    = (char*)d_ws;
    short* pk    = (short*)ws;
    float* stoch0 = (float*)(ws + WS_STOCH0);
    float* deter0 = (float*)(ws + WS_DETER0);
    short* E      = (short*)(ws + WS_E);
    float* out    = (float*)d_out;

    hipLaunchKernelGGL(pack_kernel, dim3(FR_TOT), dim3(64), 0, stream,
                       w_inp, w_gru, w_imgout, w_obsout, w_ims, w_obs, pk);
    hipLaunchKernelGGL(init_kernel, dim3(1), dim3(256), 0, stream,
                       w_init, w_imgout, ln_img_s, ln_img_b, w_ims, b_ims, stoch0, deter0);
    hipLaunchKernelGGL(embed_gemm, dim3(256), dim3(256), 0, stream, embed, pk, E);
    hipLaunchKernelGGL(scan_kernel, dim3(32), dim3(1024), 0, stream,
                       action, is_first, nzq, ln_inp_s, ln_inp_b, ln_obs_s, ln_obs_b, b_obs,
                       pk, E, stoch0, deter0, out);
    hipLaunchKernelGGL(prior_kernel, dim3(2048), dim3(64), 0, stream, nzp, b_ims, ln_img_s, ln_img_b, pk, out);
}